// Round 3
// baseline (738.067 us; speedup 1.0000x reference)
//
#include <hip/hip_runtime.h>
#include <math.h>

#define LMAXP1 33
#define EDIM   256
#define CINF   10000.0
#define DBIG   1e300

// ---------------------------------------------------------------------------
// GEMM (NT, fused bias+relu): C[Mtot x 256] = relu(A @ W^T + b)
// A rows gathered from up to 3 row-major sources (x_s, x_t, virtual row).
// BM=BN=64, BK=16, 256 threads, 4x4 micro-tile per thread.
// ---------------------------------------------------------------------------
__global__ __launch_bounds__(256)
void k_embed_gemm(const float* __restrict__ S0, int n0,
                  const float* __restrict__ S1, int n1,
                  const float* __restrict__ S2,
                  const float* __restrict__ W, const float* __restrict__ bias,
                  float* __restrict__ C, int Mtot, int K) {
    __shared__ alignas(16) float As[16][68];   // transposed: As[k][row]
    __shared__ alignas(16) float Bs[16][68];
    const int tid  = threadIdx.x;
    const int tx   = tid & 15, ty = tid >> 4;
    const int m0   = blockIdx.x * 64, nc0 = blockIdx.y * 64;
    const int lrow = tid >> 2;            // 0..63
    const int lk4  = (tid & 3) << 2;      // 0,4,8,12

    const int gr = m0 + lrow;
    const float* srow = nullptr;
    if (gr < n0)            srow = S0 + (size_t)gr * K;
    else if (gr < n0 + n1)  srow = S1 + (size_t)(gr - n0) * K;
    else if (gr < Mtot)     srow = S2;               // single virtual row
    const float* wrow = W + (size_t)(nc0 + lrow) * K;

    float acc[4][4] = {};
    for (int k0 = 0; k0 < K; k0 += 16) {
        float4 va = make_float4(0.f, 0.f, 0.f, 0.f);
        if (srow) va = *(const float4*)(srow + k0 + lk4);
        const float4 vb = *(const float4*)(wrow + k0 + lk4);
        As[lk4+0][lrow] = va.x; As[lk4+1][lrow] = va.y;
        As[lk4+2][lrow] = va.z; As[lk4+3][lrow] = va.w;
        Bs[lk4+0][lrow] = vb.x; Bs[lk4+1][lrow] = vb.y;
        Bs[lk4+2][lrow] = vb.z; Bs[lk4+3][lrow] = vb.w;
        __syncthreads();
        #pragma unroll
        for (int kk = 0; kk < 16; ++kk) {
            const float4 a4 = *(const float4*)&As[kk][ty << 2];
            const float4 b4 = *(const float4*)&Bs[kk][tx << 2];
            const float av[4] = {a4.x, a4.y, a4.z, a4.w};
            const float bv[4] = {b4.x, b4.y, b4.z, b4.w};
            #pragma unroll
            for (int i2 = 0; i2 < 4; ++i2)
                #pragma unroll
                for (int j2 = 0; j2 < 4; ++j2)
                    acc[i2][j2] = fmaf(av[i2], bv[j2], acc[i2][j2]);
        }
        __syncthreads();
    }
    #pragma unroll
    for (int i2 = 0; i2 < 4; ++i2) {
        const int grr = m0 + (ty << 2) + i2;
        if (grr >= Mtot) continue;
        #pragma unroll
        for (int j2 = 0; j2 < 4; ++j2) {
            const int gc = nc0 + (tx << 2) + j2;
            const float vv = acc[i2][j2] + bias[gc];
            C[(size_t)grr * EDIM + gc] = fmaxf(vv, 0.0f);
        }
    }
}

// ---------------------------------------------------------------------------
// Per-pair scaled edit-cost matrix (33x33), written dense (zeros outside valid)
// Emb layout: rows [0,Ns) = source, [Ns, Ns+Nt) = target, row Ns+Nt = virtual.
// ---------------------------------------------------------------------------
__global__ __launch_bounds__(256)
void k_costs(const float* __restrict__ Emb, const int* __restrict__ len_s,
             const int* __restrict__ len_t, int Ns, int Nt,
             float* __restrict__ costs) {
    __shared__ alignas(16) float Asl[LMAXP1 * EDIM];      // ~33.8 KB
    __shared__ float dtile[LMAXP1 * LMAXP1];
    __shared__ float na[LMAXP1], nb[LMAXP1];
    __shared__ float red[256];
    __shared__ float s_scale;
    const int p = blockIdx.x, tid = threadIdx.x;
    const int n = len_s[p], m = len_t[p];
    int offs = 0, offt = 0;
    for (int j = 0; j < p; ++j) { offs += len_s[j]; offt += len_t[j]; }  // uniform
    const int veRow = Ns + Nt;
    const int tbase = Ns + offt;                 // target rows base (THE fix)

    // stage A rows (rows 0..n-1 real, row n = virtual embedding)
    for (int idx = tid; idx < (n + 1) * (EDIM / 4); idx += 256) {
        const int r = idx >> 6, c = idx & 63;
        const float* src = (r < n) ? (Emb + (size_t)(offs + r) * EDIM)
                                   : (Emb + (size_t)veRow * EDIM);
        ((float4*)Asl)[r * 64 + c] = ((const float4*)src)[c];
    }
    __syncthreads();

    if (tid <= n) {                                  // ||a_i||^2
        const float4* a4 = (const float4*)(Asl + tid * EDIM);
        float s = 0.f;
        for (int k = 0; k < 64; ++k) {
            const float4 a = a4[k];
            s = fmaf(a.x, a.x, s); s = fmaf(a.y, a.y, s);
            s = fmaf(a.z, a.z, s); s = fmaf(a.w, a.w, s);
        }
        na[tid] = s;
    } else if (tid >= 64 && tid - 64 <= m) {          // ||b_j||^2
        const int j = tid - 64;
        const float* src = (j < m) ? (Emb + (size_t)(tbase + j) * EDIM)
                                   : (Emb + (size_t)veRow * EDIM);
        const float4* b4 = (const float4*)src;
        float s = 0.f;
        for (int k = 0; k < 64; ++k) {
            const float4 b = b4[k];
            s = fmaf(b.x, b.x, s); s = fmaf(b.y, b.y, s);
            s = fmaf(b.z, b.z, s); s = fmaf(b.w, b.w, s);
        }
        nb[j] = s;
    }
    __syncthreads();

    float lsum = 0.f;
    const int m1 = m + 1;
    const int cells = (n + 1) * m1;
    for (int c = tid; c < cells; c += 256) {
        const int i = c / m1, j = c - i * m1;
        const float* brow = (j < m) ? (Emb + (size_t)(tbase + j) * EDIM)
                                    : (Emb + (size_t)veRow * EDIM);
        const float4* a4 = (const float4*)(Asl + i * EDIM);
        const float4* b4 = (const float4*)brow;
        float dot = 0.f;
        #pragma unroll 8
        for (int k = 0; k < 64; ++k) {
            const float4 a = a4[k], b = b4[k];
            dot = fmaf(a.x, b.x, dot); dot = fmaf(a.y, b.y, dot);
            dot = fmaf(a.z, b.z, dot); dot = fmaf(a.w, b.w, dot);
        }
        const float sq = fmaxf(na[i] + nb[j] - 2.0f * dot, 0.0f);
        const float d  = (sq > 0.0f) ? sqrtf(sq) : 0.0f;
        dtile[i * LMAXP1 + j] = d;
        lsum += d;
    }
    red[tid] = lsum;
    __syncthreads();
    for (int s = 128; s > 0; s >>= 1) {
        if (tid < s) red[tid] += red[tid + s];
        __syncthreads();
    }
    if (tid == 0) s_scale = (float)(n * m) / red[0];
    __syncthreads();
    const float scale = s_scale;
    for (int idx = tid; idx < LMAXP1 * LMAXP1; idx += 256) {
        const int i = idx / LMAXP1, j = idx - i * LMAXP1;
        const float v = (i <= n && j <= m) ? dtile[i * LMAXP1 + j] * scale : 0.0f;
        costs[(size_t)p * (LMAXP1 * LMAXP1) + idx] = v;
    }
}

// ---------------------------------------------------------------------------
// LAP (Jonker-Volgenant) — LITERAL transcription of the reference.
// One wave per pair. Lane l <-> array index l (0..N), index 0 = dummy slot.
// u[] in LDS (indexed by row, read fresh each step, exactly like numpy).
// C materialized in LDS as fp64. v/minv/p/way/used per-lane registers.
// ---------------------------------------------------------------------------
__device__ inline int rdlane_i(int v, int l) { return __builtin_amdgcn_readlane(v, l); }
__device__ inline double shflxor_d(double x, int m) {
    union { double d; int i[2]; } u; u.d = x;
    u.i[0] = __shfl_xor(u.i[0], m);
    u.i[1] = __shfl_xor(u.i[1], m);
    return u.d;
}

__global__ __launch_bounds__(64)
void k_lap(const float* __restrict__ costs, const int* __restrict__ len_s,
           const int* __restrict__ len_t, float* __restrict__ aligns,
           float* __restrict__ geds) {
    __shared__ float  ec[LMAXP1 * LMAXP1];
    __shared__ double Cs[62 * 62];          // C[N][N], row-major, N <= 61
    __shared__ double u_s[66];              // u[0..N]
    const int p = blockIdx.x, lane = threadIdx.x;
    const int n = len_s[p], m = len_t[p], N = n + m;
    const float* cp = costs + (size_t)p * (LMAXP1 * LMAXP1);
    for (int idx = lane; idx < LMAXP1 * LMAXP1; idx += 64) ec[idx] = cp[idx];
    if (lane <= N) u_s[lane] = 0.0;
    __syncthreads();

    // Build the expanded (N x N) LSAPE matrix exactly like _lsape_align.
    for (int idx = lane; idx < N * N; idx += 64) {
        const int i = idx / N, j = idx - i * N;   // 0-based
        double cv;
        if (i < n) cv = (j < m) ? (double)ec[i * LMAXP1 + j]
                                : ((j == m + i) ? (double)ec[i * LMAXP1 + m] : CINF);
        else       cv = (j < m) ? ((i - n == j) ? (double)ec[n * LMAXP1 + j] : CINF)
                                : 0.0;
        Cs[idx] = cv;
    }
    __syncthreads();

    // Per-lane state, index = lane (0..N). Lane 0 is the dummy 0 slot.
    double v_l = 0.0, minv_l = DBIG;
    int p_l = 0, way_l = 0;
    const bool vec = (lane >= 1 && lane <= N);   // vector indices 1..N

    for (int i = 1; i <= N; ++i) {
        if (lane == 0) p_l = i;                  // p[0] = i
        minv_l = DBIG;
        int used_l = 0;
        int j0 = 0;
        while (true) {
            if (lane == j0) used_l = 1;          // used[j0] = True
            const int i0 = rdlane_i(p_l, j0);    // i0 = p[j0]
            const double u_i0 = u_s[i0];         // fresh read, like numpy
            double cur = DBIG;
            if (vec) cur = Cs[(i0 - 1) * N + (lane - 1)] - u_i0 - v_l;
            const bool unused = vec && !used_l;
            if (unused && cur < minv_l) { minv_l = cur; way_l = j0; }
            const double masked = unused ? minv_l : DBIG;
            double mv = masked;
            #pragma unroll
            for (int off = 32; off > 0; off >>= 1) mv = fmin(mv, shflxor_d(mv, off));
            const unsigned long long ball = __ballot(masked == mv);
            int j1 = __ffsll(ball) - 1;          // first-index argmin (np.argmin)
            j1 = __builtin_amdgcn_readfirstlane(j1);
            const double delta = mv;
            if (used_l && lane <= N) u_s[p_l] += delta;   // u[p[used]] += delta
            if (used_l) v_l -= delta;                      // v[used]    -= delta
            if (unused) minv_l -= delta;                   // minv[~used]-= delta
            __syncthreads();                               // publish u_s writes
            j0 = j1;
            const int pj = rdlane_i(p_l, j0);
            if (pj == 0) break;
        }
        // augment: while j0: j1=way[j0]; p[j0]=p[j1]; j0=j1
        int jj = j0;
        while (jj != 0) {
            const int j1a = rdlane_i(way_l, jj);
            const int pj1 = rdlane_i(p_l, j1a);   // p[j1a]; lane0 holds p[0]=i
            if (lane == jj) p_l = pj1;
            jj = j1a;
        }
    }

    // outputs: aligns (0/1 as float), geds
    float* ap = aligns + (size_t)p * (LMAXP1 * LMAXP1);
    for (int idx = lane; idx < LMAXP1 * LMAXP1; idx += 64) ap[idx] = 0.0f;
    __syncthreads();
    double gedv = 0.0;
    if (vec) {
        const int r0 = p_l - 1;                  // row assigned to column (lane)
        const int c0 = lane - 1;
        const int rr = (r0 < n) ? r0 : n;
        const int cc = (c0 < m) ? c0 : m;
        if (!(r0 >= n && c0 >= m)) {             // dummy-dummy -> align[n][m], forced 0
            ap[rr * LMAXP1 + cc] = 1.0f;
            gedv = (double)ec[rr * LMAXP1 + cc];
        }
    }
    #pragma unroll
    for (int off = 32; off > 0; off >>= 1) gedv += shflxor_d(gedv, off);
    if (lane == 0) geds[p] = (float)(gedv / (double)(n + m));
}

// ---------------------------------------------------------------------------
extern "C" void kernel_launch(void* const* d_in, const int* in_sizes, int n_in,
                              void* d_out, int out_size, void* d_ws, size_t ws_size,
                              hipStream_t stream) {
    const float* x_s = (const float*)d_in[0];
    const float* x_t = (const float*)d_in[1];
    const float* W1  = (const float*)d_in[2];
    const float* b1  = (const float*)d_in[3];
    const float* W2  = (const float*)d_in[4];
    const float* b2  = (const float*)d_in[5];
    const float* ve  = (const float*)d_in[6];
    const int* len_s = (const int*)d_in[7];
    const int* len_t = (const int*)d_in[8];
    const int P    = in_sizes[7];
    const int Ns   = in_sizes[0] / 2048;
    const int Nt   = in_sizes[1] / 2048;
    const int Mtot = Ns + Nt + 1;

    float* H   = (float*)d_ws;
    float* Emb = H + (size_t)Mtot * EDIM;

    float* out_aligns = (float*)d_out;
    float* out_costs  = out_aligns + (size_t)P * LMAXP1 * LMAXP1;
    float* out_geds   = out_costs  + (size_t)P * LMAXP1 * LMAXP1;

    const dim3 b256(256);
    const dim3 g1((Mtot + 63) / 64, EDIM / 64);
    // layer 1: [x_s; x_t; ve] @ W1^T -> H  (K=2048)
    k_embed_gemm<<<g1, b256, 0, stream>>>(x_s, Ns, x_t, Nt, ve, W1, b1, H, Mtot, 2048);
    // layer 2: H @ W2^T -> Emb  (K=256)
    k_embed_gemm<<<g1, b256, 0, stream>>>(H, Mtot, nullptr, 0, nullptr, W2, b2, Emb, Mtot, 256);
    // per-pair scaled cost matrices
    k_costs<<<dim3(P), b256, 0, stream>>>(Emb, len_s, len_t, Ns, Nt, out_costs);
    // per-pair LSAPE alignment + GED
    k_lap<<<dim3(P), dim3(64), 0, stream>>>(out_costs, len_s, len_t, out_aligns, out_geds);
}

// Round 4
// 493.693 us; speedup vs baseline: 1.4950x; 1.4950x over previous
//
#include <hip/hip_runtime.h>
#include <math.h>

#define LMAXP1 33
#define EDIM   256
#define CINF   10000.0f
#define FBIG   3.0e38f

// ---------------------------------------------------------------------------
// GEMM (NT, fused bias+relu): C[Mtot x 256] = relu(A @ W^T + b)
// ---------------------------------------------------------------------------
__global__ __launch_bounds__(256)
void k_embed_gemm(const float* __restrict__ S0, int n0,
                  const float* __restrict__ S1, int n1,
                  const float* __restrict__ S2,
                  const float* __restrict__ W, const float* __restrict__ bias,
                  float* __restrict__ C, int Mtot, int K) {
    __shared__ alignas(16) float As[16][68];   // transposed: As[k][row]
    __shared__ alignas(16) float Bs[16][68];
    const int tid  = threadIdx.x;
    const int tx   = tid & 15, ty = tid >> 4;
    const int m0   = blockIdx.x * 64, nc0 = blockIdx.y * 64;
    const int lrow = tid >> 2;            // 0..63
    const int lk4  = (tid & 3) << 2;      // 0,4,8,12

    const int gr = m0 + lrow;
    const float* srow = nullptr;
    if (gr < n0)            srow = S0 + (size_t)gr * K;
    else if (gr < n0 + n1)  srow = S1 + (size_t)(gr - n0) * K;
    else if (gr < Mtot)     srow = S2;               // single virtual row
    const float* wrow = W + (size_t)(nc0 + lrow) * K;

    float acc[4][4] = {};
    for (int k0 = 0; k0 < K; k0 += 16) {
        float4 va = make_float4(0.f, 0.f, 0.f, 0.f);
        if (srow) va = *(const float4*)(srow + k0 + lk4);
        const float4 vb = *(const float4*)(wrow + k0 + lk4);
        As[lk4+0][lrow] = va.x; As[lk4+1][lrow] = va.y;
        As[lk4+2][lrow] = va.z; As[lk4+3][lrow] = va.w;
        Bs[lk4+0][lrow] = vb.x; Bs[lk4+1][lrow] = vb.y;
        Bs[lk4+2][lrow] = vb.z; Bs[lk4+3][lrow] = vb.w;
        __syncthreads();
        #pragma unroll
        for (int kk = 0; kk < 16; ++kk) {
            const float4 a4 = *(const float4*)&As[kk][ty << 2];
            const float4 b4 = *(const float4*)&Bs[kk][tx << 2];
            const float av[4] = {a4.x, a4.y, a4.z, a4.w};
            const float bv[4] = {b4.x, b4.y, b4.z, b4.w};
            #pragma unroll
            for (int i2 = 0; i2 < 4; ++i2)
                #pragma unroll
                for (int j2 = 0; j2 < 4; ++j2)
                    acc[i2][j2] = fmaf(av[i2], bv[j2], acc[i2][j2]);
        }
        __syncthreads();
    }
    #pragma unroll
    for (int i2 = 0; i2 < 4; ++i2) {
        const int grr = m0 + (ty << 2) + i2;
        if (grr >= Mtot) continue;
        #pragma unroll
        for (int j2 = 0; j2 < 4; ++j2) {
            const int gc = nc0 + (tx << 2) + j2;
            const float vv = acc[i2][j2] + bias[gc];
            C[(size_t)grr * EDIM + gc] = fmaxf(vv, 0.0f);
        }
    }
}

// ---------------------------------------------------------------------------
// Per-pair scaled edit-cost matrix (33x33), written dense (zeros outside valid)
// Emb layout: rows [0,Ns) = source, [Ns, Ns+Nt) = target, row Ns+Nt = virtual.
// ---------------------------------------------------------------------------
__global__ __launch_bounds__(256)
void k_costs(const float* __restrict__ Emb, const int* __restrict__ len_s,
             const int* __restrict__ len_t, int Ns, int Nt,
             float* __restrict__ costs) {
    __shared__ alignas(16) float Asl[LMAXP1 * EDIM];      // ~33.8 KB
    __shared__ float dtile[LMAXP1 * LMAXP1];
    __shared__ float na[LMAXP1], nb[LMAXP1];
    __shared__ float red[256];
    __shared__ float s_scale;
    const int p = blockIdx.x, tid = threadIdx.x;
    const int n = len_s[p], m = len_t[p];
    int offs = 0, offt = 0;
    for (int j = 0; j < p; ++j) { offs += len_s[j]; offt += len_t[j]; }  // uniform
    const int veRow = Ns + Nt;
    const int tbase = Ns + offt;                 // target rows base

    for (int idx = tid; idx < (n + 1) * (EDIM / 4); idx += 256) {
        const int r = idx >> 6, c = idx & 63;
        const float* src = (r < n) ? (Emb + (size_t)(offs + r) * EDIM)
                                   : (Emb + (size_t)veRow * EDIM);
        ((float4*)Asl)[r * 64 + c] = ((const float4*)src)[c];
    }
    __syncthreads();

    if (tid <= n) {                                  // ||a_i||^2
        const float4* a4 = (const float4*)(Asl + tid * EDIM);
        float s = 0.f;
        for (int k = 0; k < 64; ++k) {
            const float4 a = a4[k];
            s = fmaf(a.x, a.x, s); s = fmaf(a.y, a.y, s);
            s = fmaf(a.z, a.z, s); s = fmaf(a.w, a.w, s);
        }
        na[tid] = s;
    } else if (tid >= 64 && tid - 64 <= m) {          // ||b_j||^2
        const int j = tid - 64;
        const float* src = (j < m) ? (Emb + (size_t)(tbase + j) * EDIM)
                                   : (Emb + (size_t)veRow * EDIM);
        const float4* b4 = (const float4*)src;
        float s = 0.f;
        for (int k = 0; k < 64; ++k) {
            const float4 b = b4[k];
            s = fmaf(b.x, b.x, s); s = fmaf(b.y, b.y, s);
            s = fmaf(b.z, b.z, s); s = fmaf(b.w, b.w, s);
        }
        nb[j] = s;
    }
    __syncthreads();

    float lsum = 0.f;
    const int m1 = m + 1;
    const int cells = (n + 1) * m1;
    for (int c = tid; c < cells; c += 256) {
        const int i = c / m1, j = c - i * m1;
        const float* brow = (j < m) ? (Emb + (size_t)(tbase + j) * EDIM)
                                    : (Emb + (size_t)veRow * EDIM);
        const float4* a4 = (const float4*)(Asl + i * EDIM);
        const float4* b4 = (const float4*)brow;
        float dot = 0.f;
        #pragma unroll 8
        for (int k = 0; k < 64; ++k) {
            const float4 a = a4[k], b = b4[k];
            dot = fmaf(a.x, b.x, dot); dot = fmaf(a.y, b.y, dot);
            dot = fmaf(a.z, b.z, dot); dot = fmaf(a.w, b.w, dot);
        }
        const float sq = fmaxf(na[i] + nb[j] - 2.0f * dot, 0.0f);
        const float d  = (sq > 0.0f) ? sqrtf(sq) : 0.0f;
        dtile[i * LMAXP1 + j] = d;
        lsum += d;
    }
    red[tid] = lsum;
    __syncthreads();
    for (int s = 128; s > 0; s >>= 1) {
        if (tid < s) red[tid] += red[tid + s];
        __syncthreads();
    }
    if (tid == 0) s_scale = (float)(n * m) / red[0];
    __syncthreads();
    const float scale = s_scale;
    for (int idx = tid; idx < LMAXP1 * LMAXP1; idx += 256) {
        const int i = idx / LMAXP1, j = idx - i * LMAXP1;
        const float v = (i <= n && j <= m) ? dtile[i * LMAXP1 + j] * scale : 0.0f;
        costs[(size_t)p * (LMAXP1 * LMAXP1) + idx] = v;
    }
}

// ---------------------------------------------------------------------------
// LAP (Jonker-Volgenant), literal indexing (lane = array index 0..N).
// All state in registers: v, minv, way, p per-lane; u tracked per-COLUMN
// (ucol[lane] == u[p[lane]], migrated during augmentation). No LDS in the
// inner loop except the C-row read. fp32. Min-reduce via DPP chain;
// first-index argmin via ballot+ffsll (matches np.argmin tie-break).
// ---------------------------------------------------------------------------
__device__ inline int rdlane_i(int v, int l) { return __builtin_amdgcn_readlane(v, l); }
__device__ inline float rdlane_f(float v, int l) {
    return __int_as_float(__builtin_amdgcn_readlane(__float_as_int(v), l));
}
// full-wave min; result valid in lane 63, broadcast via readlane.
__device__ inline float wave_min64(float x) {
#define DPPMIN(ctrl) { int t_ = __builtin_amdgcn_update_dpp(               \
        __float_as_int(x), __float_as_int(x), (ctrl), 0xf, 0xf, false);    \
        x = fminf(x, __int_as_float(t_)); }
    DPPMIN(0xB1)   // quad_perm [1,0,3,2]  : xor 1
    DPPMIN(0x4E)   // quad_perm [2,3,0,1]  : xor 2
    DPPMIN(0x141)  // row_half_mirror      : xor 4
    DPPMIN(0x140)  // row_mirror           : xor 8
    DPPMIN(0x142)  // row_bcast15          : cross 16 (invalid lanes keep old)
    DPPMIN(0x143)  // row_bcast31          : cross 32
#undef DPPMIN
    return rdlane_f(x, 63);
}

__global__ __launch_bounds__(64)
void k_lap(const float* __restrict__ costs, const int* __restrict__ len_s,
           const int* __restrict__ len_t, float* __restrict__ aligns,
           float* __restrict__ geds) {
    __shared__ float ec[LMAXP1 * LMAXP1];
    __shared__ float Cs[62 * 64];           // rows/cols 1..N at [r*64+c]
    const int p = blockIdx.x, lane = threadIdx.x;
    const int n = len_s[p], m = len_t[p], N = n + m;
    const float* cp = costs + (size_t)p * (LMAXP1 * LMAXP1);
    for (int idx = lane; idx < LMAXP1 * LMAXP1; idx += 64) ec[idx] = cp[idx];
    __syncthreads();

    // Build expanded (N x N) LSAPE matrix exactly like _lsape_align (fp32).
    for (int r = 1; r <= N; ++r) {
        float cv = CINF;
        const int i0b = r - 1, j0b = lane - 1;
        if (lane >= 1 && lane <= N) {
            if (i0b < n) cv = (j0b < m) ? ec[i0b * LMAXP1 + j0b]
                                        : ((j0b == m + i0b) ? ec[i0b * LMAXP1 + m] : CINF);
            else         cv = (j0b < m) ? ((i0b - n == j0b) ? ec[n * LMAXP1 + j0b] : CINF)
                                        : 0.0f;
        }
        Cs[(r << 6) + lane] = cv;
    }
    __syncthreads();

    // Per-lane state, index = lane (0..N). Lane 0 = dummy slot 0.
    float v_l = 0.0f, minv_l = FBIG, ucol = 0.0f;   // ucol = u[p[lane]]
    int p_l = 0, way_l = 0;
    const bool vec = (lane >= 1 && lane <= N);

    for (int i = 1; i <= N; ++i) {
        if (lane == 0) { p_l = i; ucol = 0.0f; }    // p[0]=i, u[i]=0 (fresh row)
        minv_l = FBIG;
        int used_l = 0;
        int j0 = 0;
        while (true) {
            if (lane == j0) used_l = 1;             // used[j0] = True
            const int   i0   = rdlane_i(p_l, j0);   // i0 = p[j0]  (1-based row)
            const float u_i0 = rdlane_f(ucol, j0);  // u[p[j0]]
            const float cur  = Cs[(i0 << 6) + lane] - u_i0 - v_l;
            const bool unused = vec && !used_l;
            if (unused && cur < minv_l) { minv_l = cur; way_l = j0; }
            const float masked = unused ? minv_l : FBIG;
            const float mv = wave_min64(masked);
            const unsigned long long ball = __ballot(masked == mv);
            int j1 = __ffsll(ball) - 1;             // first-index argmin
            j1 = __builtin_amdgcn_readfirstlane(j1);
            const float delta = mv;
            if (used_l) { ucol += delta; v_l -= delta; }  // u[p[used]]+=, v[used]-=
            if (unused) minv_l -= delta;                   // minv[~used]-=
            j0 = j1;
            const int pj = rdlane_i(p_l, j0);
            if (pj == 0) break;
        }
        // augment: while j0: j1=way[j0]; p[j0]=p[j1]; j0=j1  (u follows p)
        int jj = j0;
        while (jj != 0) {
            const int   j1a = rdlane_i(way_l, jj);
            const int   pn  = rdlane_i(p_l, j1a);
            const float un  = rdlane_f(ucol, j1a);
            if (lane == jj) { p_l = pn; ucol = un; }
            jj = j1a;
        }
    }

    // outputs: aligns (0/1 as float), geds
    float* ap = aligns + (size_t)p * (LMAXP1 * LMAXP1);
    for (int idx = lane; idx < LMAXP1 * LMAXP1; idx += 64) ap[idx] = 0.0f;
    __syncthreads();
    float gedv = 0.0f;
    if (vec) {
        const int r0 = p_l - 1;                  // row assigned to column (lane)
        const int c0 = lane - 1;
        const int rr = (r0 < n) ? r0 : n;
        const int cc = (c0 < m) ? c0 : m;
        if (!(r0 >= n && c0 >= m)) {             // dummy-dummy -> align[n][m], stays 0
            ap[rr * LMAXP1 + cc] = 1.0f;
            gedv = ec[rr * LMAXP1 + cc];
        }
    }
    #pragma unroll
    for (int off = 32; off > 0; off >>= 1) gedv += __shfl_xor(gedv, off);
    if (lane == 0) geds[p] = gedv / (float)(n + m);
}

// ---------------------------------------------------------------------------
extern "C" void kernel_launch(void* const* d_in, const int* in_sizes, int n_in,
                              void* d_out, int out_size, void* d_ws, size_t ws_size,
                              hipStream_t stream) {
    const float* x_s = (const float*)d_in[0];
    const float* x_t = (const float*)d_in[1];
    const float* W1  = (const float*)d_in[2];
    const float* b1  = (const float*)d_in[3];
    const float* W2  = (const float*)d_in[4];
    const float* b2  = (const float*)d_in[5];
    const float* ve  = (const float*)d_in[6];
    const int* len_s = (const int*)d_in[7];
    const int* len_t = (const int*)d_in[8];
    const int P    = in_sizes[7];
    const int Ns   = in_sizes[0] / 2048;
    const int Nt   = in_sizes[1] / 2048;
    const int Mtot = Ns + Nt + 1;

    float* H   = (float*)d_ws;
    float* Emb = H + (size_t)Mtot * EDIM;

    float* out_aligns = (float*)d_out;
    float* out_costs  = out_aligns + (size_t)P * LMAXP1 * LMAXP1;
    float* out_geds   = out_costs  + (size_t)P * LMAXP1 * LMAXP1;

    const dim3 b256(256);
    const dim3 g1((Mtot + 63) / 64, EDIM / 64);
    k_embed_gemm<<<g1, b256, 0, stream>>>(x_s, Ns, x_t, Nt, ve, W1, b1, H, Mtot, 2048);
    k_embed_gemm<<<g1, b256, 0, stream>>>(H, Mtot, nullptr, 0, nullptr, W2, b2, Emb, Mtot, 256);
    k_costs<<<dim3(P), b256, 0, stream>>>(Emb, len_s, len_t, Ns, Nt, out_costs);
    k_lap<<<dim3(P), dim3(64), 0, stream>>>(out_costs, len_s, len_t, out_aligns, out_geds);
}